// Round 2
// baseline (237.448 us; speedup 1.0000x reference)
//
#include <hip/hip_runtime.h>
#include <math.h>

// ---------------- constants ----------------
#define KDIM    65536
#define NNODES  100
#define OUTC    60
#define YW      64          // padded col width of Y
#define YSLAB   (NNODES*YW) // 6400 floats per hk

// DMA GEMM chunking: 16 stages of BK=64 -> 1024 k per block, 64 k-chunks
#define BK5     64
#define ITERS5  16
#define SLAB5   (BK5*ITERS5)    // 1024
#define NKC5    (KDIM/SLAB5)    // 64
// f32 fallback GEMM chunking
#define CHUNK   256
#define NKC     256
#define STEPS   (CHUNK/32)

// ws layout (float offsets)
#define WS_S    0           // (unused now, kept for layout stability)
#define WS_Y    10048       // 6*6400 = 38400 floats
#define WS_E    48448       // 2*6000 = 12000 floats
// bf16 x scratch (byte offsets)
#define XB_OFF_BYTES   245760ull
#define XB_BYTES       (100ull*65536ull*2ull)         // 13107200
#define WS_NEED_BYTES  (XB_OFF_BYTES + XB_BYTES)      // 13352960
// non-atomic partial-Y buffer (NKC5 * 6 * YSLAB floats) after xb
#define YP_OFF_BYTES   WS_NEED_BYTES
#define YP_FLOATS      ((size_t)NKC5 * 6 * YSLAB)     // 2457600
#define WS_NEED2_BYTES (YP_OFF_BYTES + YP_FLOATS * 4ull) // 23183360

typedef short bf16x8 __attribute__((ext_vector_type(8)));
typedef float f32x4  __attribute__((ext_vector_type(4)));
typedef unsigned short ushort8 __attribute__((ext_vector_type(8)));

__device__ inline unsigned short f2bf(float f) {
    union { float f; unsigned u; } x; x.f = f;
    unsigned r = x.u + 0x7FFFu + ((x.u >> 16) & 1u);   // RNE (finite inputs)
    return (unsigned short)(r >> 16);
}

// ---------------- pass 1: x f32 -> bf16 (pure stream) --------------------------
__global__ __launch_bounds__(256) void k_cvt_x(const float* __restrict__ x,
                                               ushort8* __restrict__ xb) {
    int g = blockIdx.x * 256 + threadIdx.x;
    for (int i = g; i < 819200; i += 204800) {
        const float4 lo = ((const float4*)x)[2 * i];
        const float4 hi = ((const float4*)x)[2 * i + 1];
        ushort8 o;
        o[0] = f2bf(lo.x); o[1] = f2bf(lo.y); o[2] = f2bf(lo.z); o[3] = f2bf(lo.w);
        o[4] = f2bf(hi.x); o[5] = f2bf(hi.y); o[6] = f2bf(hi.z); o[7] = f2bf(hi.w);
        xb[i] = o;
    }
}

// ---------------- pass 2: pipelined DMA GEMM (counted vmcnt) -------------------
// grid (6, NKC5), block 512 = 8 waves: wave = (mg<<2)|ng; ng owns 16 cols,
// mg owns 4 (or 3) m-tiles. Per stage each wave issues EXACTLY 4
// global_load_lds (A: 14 real + 2 pad; W: 15 real + 1 clamped pad), so the
// software pipeline can use s_waitcnt vmcnt(4): stage t+1 issued, wait until
// stage t's 4 loads landed, barrier, compute. Loads stay in flight across
// barriers instead of the vmcnt(0)-drain __syncthreads forces.
template <bool DIRECT>
__global__ __launch_bounds__(512) void k_gemm6(const unsigned short* __restrict__ xb,
                                               const float* __restrict__ wa,
                                               const float* __restrict__ wc,
                                               float* __restrict__ Y,
                                               float* __restrict__ Yp) {
    __shared__ unsigned short Ab[2][112 * BK5];   // 2 x 14336 B
    __shared__ float          Wf[2][4096];        // 2 x 16384 B (3840 real + pad)
    __shared__ float          padlds[256];        // 1 KB dummy DMA target
    const int hk   = blockIdx.x;
    const int kc   = blockIdx.y;
    const int wave = threadIdx.x >> 6;
    const int lane = threadIdx.x & 63;
    const int n16  = lane & 15;
    const int quad = lane >> 4;
    const int ng   = wave & 3;
    const int mg   = wave >> 2;
    const int c0   = ng * 16;
    const int cidx = min(c0 + n16, OUTC - 1);
    const int NT   = 4 - mg;                 // mg=0: tiles 0..3, mg=1: tiles 4..6
    const int kb0  = kc * SLAB5;

    const float* Wg = (hk < 3 ? wa : wc) + (size_t)(hk % 3) * ((size_t)KDIM * OUTC);

    auto DMA = [&](int buf, int kb) {
        const float* wsrc = Wg + (size_t)kb * OUTC;
#pragma unroll
        for (int j5 = 0; j5 < 4; ++j5) {
            int j = wave + j5 * 8;           // uniform 4 loads per wave
            const void* src; void* dst;
            if (j < 16) {                    // A side: j 0..13 real, 14..15 pad
                int chunk = j * 64 + lane;
                int m  = chunk >> 3;
                int cc = (chunk & 7) ^ (m & 7);
                src = xb + (size_t)min(m, NNODES - 1) * KDIM + kb + cc * 8;
                dst = (j < 14) ? (void*)&Ab[buf][j * 512] : (void*)padlds;
            } else {                         // W side: jj 0..14 real, 15 pad
                int jj = j - 16;
                src = wsrc + (jj == 15 ? 0 : jj * 256) + lane * 4;
                dst = &Wf[buf][jj * 256];
            }
            __builtin_amdgcn_global_load_lds(
                (const __attribute__((address_space(1))) void*)src,
                (__attribute__((address_space(3))) void*)dst, 16, 0, 0);
        }
    };

    DMA(0, kb0);
    f32x4 acc[4] = {};

#pragma unroll
    for (int it = 0; it < ITERS5; ++it) {
        if (it + 1 < ITERS5) {
            DMA((it + 1) & 1, kb0 + (it + 1) * BK5);   // stage t+1 in flight
            asm volatile("s_waitcnt vmcnt(4)" ::: "memory");  // stage t landed
        } else {
            asm volatile("s_waitcnt vmcnt(0)" ::: "memory");
        }
        __builtin_amdgcn_s_barrier();                   // all waves see stage t
        asm volatile("" ::: "memory");
        const unsigned short* A = Ab[it & 1];
        const float*          B = Wf[it & 1];
#pragma unroll
        for (int s = 0; s < 2; ++s) {
            bf16x8 bfr;
#pragma unroll
            for (int jq = 0; jq < 8; ++jq) {
                int jj = (jq + quad * 2) & 7;
                bfr[jj] = (short)f2bf(B[(s * 32 + quad * 8 + jj) * OUTC + cidx]);
            }
            int ch = (s * 4 + quad) ^ (n16 & 7);
#pragma unroll
            for (int t = 0; t < 4; ++t) {
                if (t < NT) {
                    int T = mg * 4 + t;
                    bf16x8 afr = *(const bf16x8*)(A + (T * 16 + n16) * BK5 + ch * 8);
                    acc[t] = __builtin_amdgcn_mfma_f32_16x16x32_bf16(afr, bfr, acc[t], 0, 0, 0);
                }
            }
        }
        asm volatile("" ::: "memory");
        __builtin_amdgcn_s_barrier();                   // buf[it&1] free for reuse
    }

    float* Yb = DIRECT ? (Yp + ((size_t)kc * 6 + hk) * YSLAB) : (Y + hk * YSLAB);
#pragma unroll
    for (int t = 0; t < 4; ++t) {
        if (t < NT) {
            int T = mg * 4 + t;
#pragma unroll
            for (int r = 0; r < 4; ++r) {
                int row = T * 16 + quad * 4 + r;
                if (row < NNODES) {
                    if (DIRECT) Yb[row * YW + c0 + n16] = acc[t][r];
                    else        atomicAdd(&Yb[row * YW + c0 + n16], acc[t][r]);
                }
            }
        }
    }
}

// ---------------- reduce partial Y slabs: Y[i] = sum_kc Yp[kc][i] --------------
__global__ __launch_bounds__(256) void k_reduce(const float* __restrict__ P,
                                                float* __restrict__ Y) {
    int g = blockIdx.x * 256 + threadIdx.x;
    if (g >= 9600) return;
    const f32x4* p = (const f32x4*)P + g;
    f32x4 s = {};
#pragma unroll 4
    for (int kc = 0; kc < NKC5; ++kc) s += p[(size_t)kc * 9600];
    ((f32x4*)Y)[g] = s;
}

// ---------------- fallback f32 GEMM (used only if ws is too small) -------------
__global__ __launch_bounds__(256, 2) void k_gemm_f32(const float* __restrict__ x,
                                                     const float* __restrict__ wa,
                                                     const float* __restrict__ wc,
                                                     float* __restrict__ Y) {
    const int hk   = blockIdx.x;
    const int kc   = blockIdx.y;
    const int wave = threadIdx.x >> 6;
    const int lane = threadIdx.x & 63;
    const int n16  = lane & 15;
    const int quad = lane >> 4;
    const float* W = (hk < 3 ? wa : wc) + (size_t)(hk % 3) * ((size_t)KDIM * OUTC);
    const int c0   = wave * 16;
    const int cidx = min(c0 + n16, OUTC - 1);
    const int kb0  = kc * CHUNK + quad * 8;
    const float* ap[7];
#pragma unroll
    for (int t = 0; t < 7; ++t)
        ap[t] = x + (size_t)min(n16 + 16 * t, NNODES - 1) * KDIM + kb0;
    const float* bp = W + (size_t)kb0 * OUTC + cidx;
    f32x4 acc[7] = {};
#pragma unroll 2
    for (int s = 0; s < STEPS; ++s) {
        bf16x8 bfr;
        const float* q = bp + (size_t)s * 32 * OUTC;
#pragma unroll
        for (int j = 0; j < 8; ++j) bfr[j] = (short)f2bf(q[j * OUTC]);
#pragma unroll
        for (int t = 0; t < 7; ++t) {
            const float* p = ap[t] + s * 32;
            float4 lo = *(const float4*)p;
            float4 hi = *(const float4*)(p + 4);
            bf16x8 afr;
            afr[0] = (short)f2bf(lo.x); afr[1] = (short)f2bf(lo.y);
            afr[2] = (short)f2bf(lo.z); afr[3] = (short)f2bf(lo.w);
            afr[4] = (short)f2bf(hi.x); afr[5] = (short)f2bf(hi.y);
            afr[6] = (short)f2bf(hi.z); afr[7] = (short)f2bf(hi.w);
            acc[t] = __builtin_amdgcn_mfma_f32_16x16x32_bf16(afr, bfr, acc[t], 0, 0, 0);
        }
    }
    float* Yb = Y + hk * YSLAB;
#pragma unroll
    for (int t = 0; t < 7; ++t)
#pragma unroll
        for (int r = 0; r < 4; ++r) {
            int row = t * 16 + quad * 4 + r;
            if (row < NNODES)
                atomicAdd(&Yb[row * YW + c0 + n16], acc[t][r]);
        }
}

// ------- kernel 3: build S in LDS + emb = tanh(cheb) + vnr  (fused) ------------
__global__ __launch_bounds__(128) void k_emb(const int* __restrict__ ei,
                                             const float* __restrict__ Y,
                                             const float* __restrict__ vnr,
                                             const float* __restrict__ avw,
                                             const float* __restrict__ avb,
                                             const float* __restrict__ cvw,
                                             const float* __restrict__ cvb,
                                             const float* __restrict__ acb,
                                             const float* __restrict__ ccb,
                                             const float* __restrict__ afcb,
                                             const float* __restrict__ cfcb,
                                             float* __restrict__ E,
                                             float* __restrict__ out) {
    __shared__ float Sp[NNODES * 101];
    __shared__ float y0[NNODES], y1[NNODES], y2[NNODES], t2[NNODES];
    __shared__ int   deg[NNODES];
    __shared__ float dinv[NNODES];
    const int b = blockIdx.x, head = b / OUTC, c = b % OUTC;
    const int t = threadIdx.x;
    const int* src = ei;
    const int* dst = ei + 1600;

    for (int i = t; i < NNODES * 101; i += 128) Sp[i] = 0.f;
    if (t < NNODES) deg[t] = 0;
    __syncthreads();
    for (int e = t; e < 1600; e += 128) atomicAdd(&deg[src[e]], 1);
    __syncthreads();
    if (t < NNODES) { int d = deg[t]; dinv[t] = (d > 0) ? rsqrtf((float)d) : 0.f; }
    __syncthreads();
    for (int e = t; e < 1600; e += 128) {
        int s = src[e], d = dst[e];
        atomicAdd(&Sp[d * 101 + s], -dinv[s] * dinv[d]);
    }
    const float* Yh = Y + (size_t)head * 3 * YSLAB;
    if (t < NNODES) {
        y0[t] = Yh[t * YW + c];
        y1[t] = Yh[YSLAB + t * YW + c];
        y2[t] = Yh[2 * YSLAB + t * YW + c];
    }
    if (b == 0 && t < 101) out[t] = (t < 100) ? afcb[t] : cfcb[0];
    __syncthreads();

    float z1 = 0.f, s2 = 0.f;
    if (t < NNODES) {
        const float* sr = Sp + t * 101;
        for (int m = 0; m < NNODES; ++m) { z1 += sr[m] * y1[m]; s2 += sr[m] * y2[m]; }
        t2[t] = s2;
    }
    __syncthreads();
    if (t < NNODES) {
        const float* sr = Sp + t * 101;
        float t3 = 0.f;
        for (int m = 0; m < NNODES; ++m) t3 += sr[m] * t2[m];
        const float* cb = head ? ccb : acb;
        const float* vw = head ? cvw : avw;
        const float* vb = head ? cvb : avb;
        float u  = y0[t] + z1 + 2.f * t3 - y2[t] + cb[c];
        float vs = vnr[0] * vw[c]        + vb[c]
                 + vnr[1] * vw[OUTC + c] + vb[OUTC + c]
                 + vnr[2] * vw[2*OUTC+c] + vb[2*OUTC+c];
        E[head * (NNODES * OUTC) + t * OUTC + c] = tanhf(u) + vs;
    }
}

// ---------------- kernel 4: heads — grid 240, 25 flat rows per block -----------
__global__ __launch_bounds__(128) void k_heads(const float* __restrict__ E,
                                               const float* __restrict__ afw,
                                               const float* __restrict__ cfw,
                                               float* __restrict__ out) {
    __shared__ float ea[25], ec[25];
    const int b = blockIdx.x, t = threadIdx.x;
    const int f0 = b * 25;
    if (t < 25) {
        ea[t] = E[f0 + t];
        ec[t] = E[NNODES * OUTC + f0 + t];
    }
    __syncthreads();
    if (t < 100) {
        float s = 0.f;
#pragma unroll
        for (int i = 0; i < 25; ++i) s += ea[i] * afw[(size_t)(f0 + i) * 100 + t];
        atomicAdd(&out[t], s);
    } else if (t == 100) {
        float s = 0.f;
#pragma unroll
        for (int i = 0; i < 25; ++i) s += ec[i] * cfw[f0 + i];
        atomicAdd(&out[100], s);
    }
}

// ---------------- launch ----------------
extern "C" void kernel_launch(void* const* d_in, const int* in_sizes, int n_in,
                              void* d_out, int out_size, void* d_ws, size_t ws_size,
                              hipStream_t stream) {
    const float* x    = (const float*)d_in[0];
    const int*   ei   = (const int*)  d_in[1];
    const float* vnr  = (const float*)d_in[2];
    const float* wa   = (const float*)d_in[3];
    const float* acb  = (const float*)d_in[4];
    const float* wc   = (const float*)d_in[5];
    const float* ccb  = (const float*)d_in[6];
    const float* avw  = (const float*)d_in[7];
    const float* avb  = (const float*)d_in[8];
    const float* cvw  = (const float*)d_in[9];
    const float* cvb  = (const float*)d_in[10];
    const float* afw  = (const float*)d_in[11];
    const float* afcb = (const float*)d_in[12];
    const float* cfw  = (const float*)d_in[13];
    const float* cfcb = (const float*)d_in[14];

    float* ws = (float*)d_ws;
    float* Y  = ws + WS_Y;
    float* E  = ws + WS_E;
    float* out = (float*)d_out;

    if (ws_size >= WS_NEED2_BYTES) {
        // DIRECT path: no memset, no atomics, 5 dispatches total
        unsigned short* xb = (unsigned short*)((char*)d_ws + XB_OFF_BYTES);
        float* Yp = (float*)((char*)d_ws + YP_OFF_BYTES);
        k_cvt_x<<<800, 256, 0, stream>>>(x, (ushort8*)xb);
        k_gemm6<true><<<dim3(6, NKC5), 512, 0, stream>>>(xb, wa, wc, Y, Yp);
        k_reduce<<<38, 256, 0, stream>>>(Yp, Y);
    } else if (ws_size >= WS_NEED_BYTES) {
        unsigned short* xb = (unsigned short*)((char*)d_ws + XB_OFF_BYTES);
        hipMemsetAsync((char*)d_ws + WS_Y * 4, 0, (WS_E - WS_Y) * 4, stream);
        k_cvt_x<<<800, 256, 0, stream>>>(x, (ushort8*)xb);
        k_gemm6<false><<<dim3(6, NKC5), 512, 0, stream>>>(xb, wa, wc, Y, nullptr);
    } else {
        hipMemsetAsync((char*)d_ws + WS_Y * 4, 0, (WS_E - WS_Y) * 4, stream);
        k_gemm_f32<<<dim3(6, NKC), 256, 0, stream>>>(x, wa, wc, Y);
    }

    k_emb<<<120, 128, 0, stream>>>(ei, Y, vnr, avw, avb, cvw, cvb,
                                   acb, ccb, afcb, cfcb, E, out);
    k_heads<<<240, 128, 0, stream>>>(E, afw, cfw, out);
}

// Round 3
// 204.398 us; speedup vs baseline: 1.1617x; 1.1617x over previous
//
#include <hip/hip_runtime.h>
#include <math.h>

// ---------------- constants ----------------
#define KDIM    65536
#define NNODES  100
#define OUTC    60
#define YW      64          // padded col width of Y
#define YSLAB   (NNODES*YW) // 6400 floats per hk

// DMA GEMM chunking: 16 stages of BK=64 -> 1024 k per block
#define BK5     64
#define ITERS5  16
#define SLAB5   (BK5*ITERS5)    // 1024
#define NKC5    (KDIM/SLAB5)    // 64
// f32 fallback GEMM chunking
#define CHUNK   256
#define NKC     256
#define STEPS   (CHUNK/32)

// ws layout (float offsets)
#define WS_Y    10048       // 6*6400 = 38400 floats
#define WS_E    48448       // 2*6000 = 12000 floats
// bf16 x scratch (byte offsets)
#define XB_OFF_BYTES   245760ull
#define XB_BYTES       (100ull*65536ull*2ull)         // 13107200
#define WS_NEED_BYTES  (XB_OFF_BYTES + XB_BYTES)      // 13352960

typedef short bf16x8 __attribute__((ext_vector_type(8)));
typedef float f32x4  __attribute__((ext_vector_type(4)));
typedef unsigned short ushort8 __attribute__((ext_vector_type(8)));

__device__ inline unsigned short f2bf(float f) {
    union { float f; unsigned u; } x; x.f = f;
    unsigned r = x.u + 0x7FFFu + ((x.u >> 16) & 1u);   // RNE (finite inputs)
    return (unsigned short)(r >> 16);
}

// ------- pass 1: x f32 -> bf16 (pure stream) + zero Y accumulation region ------
__global__ __launch_bounds__(256) void k_cvt_x(const float* __restrict__ x,
                                               ushort8* __restrict__ xb,
                                               float* __restrict__ Y) {
    int g = blockIdx.x * 256 + threadIdx.x;
    if (g < 9600) ((f32x4*)Y)[g] = (f32x4){};   // zero 6*6400 floats for atomics
    for (int i = g; i < 819200; i += 204800) {
        const float4 lo = ((const float4*)x)[2 * i];
        const float4 hi = ((const float4*)x)[2 * i + 1];
        ushort8 o;
        o[0] = f2bf(lo.x); o[1] = f2bf(lo.y); o[2] = f2bf(lo.z); o[3] = f2bf(lo.w);
        o[4] = f2bf(hi.x); o[5] = f2bf(hi.y); o[6] = f2bf(hi.z); o[7] = f2bf(hi.w);
        xb[i] = o;
    }
}

// ---------------- pass 2: GEMM, W direct-to-VGPR, A via LDS DMA ----------------
// 1-D grid 384, XCD-swizzled so the 6 hk-blocks of one kc share an XCD (A L2
// reuse). Block 256 = 4 waves; wave = ng (16 cols), each wave does 7 m-tiles.
// Per stage per wave: 4 A global_load_lds (14 real + 2 pad across waves) and
// 16 B global_load_dword f32 (stride-240B gather, reg double-buffered). Exact
// count 20/stage -> s_waitcnt vmcnt(20): stage t+1 loads stay in flight across
// both barriers; no W LDS staging, no f2bf feeding from LDS, no W bank
// conflicts. B f2bf happens on registers in the compute phase.
__global__ __launch_bounds__(256) void k_gemm7(const unsigned short* __restrict__ xb,
                                               const float* __restrict__ wa,
                                               const float* __restrict__ wc,
                                               float* __restrict__ Y) {
    __shared__ unsigned short Ab[2][14 * 512];   // 2 x 14336 B
    __shared__ unsigned short padlds[512];       // 1 KB dummy DMA target
    const int b    = blockIdx.x;
    const int lo8  = b & 7, q = b >> 3;
    const int hk   = q % 6;
    const int kc   = lo8 + 8 * (q / 6);          // 6 hk-blocks of kc: ids 8 apart
    const int wave = threadIdx.x >> 6;
    const int lane = threadIdx.x & 63;
    const int n16  = lane & 15;
    const int quad = lane >> 4;
    const int c0   = wave * 16;
    const int cidx = min(c0 + n16, OUTC - 1);    // cols 60..63 junk -> Y pad cols
    const int kb0  = kc * SLAB5;

    const float* Wg = (hk < 3 ? wa : wc) + (size_t)(hk % 3) * ((size_t)KDIM * OUTC);

    auto DMA = [&](int buf, int kb) {
#pragma unroll
        for (int j5 = 0; j5 < 4; ++j5) {
            int j = wave + j5 * 4;               // uniform 4 loads/wave
            int chunk = j * 64 + lane;
            int m  = chunk >> 3;
            int cc = (chunk & 7) ^ (m & 7);
            const unsigned short* src =
                xb + (size_t)min(m, NNODES - 1) * KDIM + kb + cc * 8;
            void* dst = (j < 14) ? (void*)&Ab[buf][j * 512] : (void*)padlds;
            __builtin_amdgcn_global_load_lds(
                (const __attribute__((address_space(1))) void*)src,
                (__attribute__((address_space(3))) void*)dst, 16, 0, 0);
        }
    };

    float breg[2][16];                           // static-indexed (full unroll)
    auto LOADB = [&](int pb, int kb) {
        const float* base = Wg + (size_t)(kb + quad * 8) * OUTC + cidx;
#pragma unroll
        for (int s = 0; s < 2; ++s)
#pragma unroll
            for (int j = 0; j < 8; ++j)
                breg[pb][s * 8 + j] = base[(s * 32 + j) * OUTC];
    };

    DMA(0, kb0);
    LOADB(0, kb0);
    f32x4 acc[7] = {};

#pragma unroll
    for (int it = 0; it < ITERS5; ++it) {
        if (it + 1 < ITERS5) {
            DMA((it + 1) & 1, kb0 + (it + 1) * BK5);
            LOADB((it + 1) & 1, kb0 + (it + 1) * BK5);
            asm volatile("s_waitcnt vmcnt(20)" ::: "memory");  // stage t landed
        } else {
            asm volatile("s_waitcnt vmcnt(0)" ::: "memory");
        }
        __builtin_amdgcn_s_barrier();            // buf[it&1] ready for all waves
        const unsigned short* A = Ab[it & 1];
#pragma unroll
        for (int s = 0; s < 2; ++s) {
            bf16x8 bfr;
#pragma unroll
            for (int j = 0; j < 8; ++j)
                bfr[j] = (short)f2bf(breg[it & 1][s * 8 + j]);
            int ch = (s * 4 + quad) ^ (n16 & 7);
#pragma unroll
            for (int t = 0; t < 7; ++t) {
                bf16x8 afr = *(const bf16x8*)(A + (t * 16 + n16) * BK5 + ch * 8);
                acc[t] = __builtin_amdgcn_mfma_f32_16x16x32_bf16(afr, bfr, acc[t], 0, 0, 0);
            }
        }
        __builtin_amdgcn_s_barrier();            // all reads of buf[it&1] done
    }

    // D layout: col = lane&15, row = quad*4 + r within 16x16 tile
    float* Yb = Y + hk * YSLAB;
#pragma unroll
    for (int t = 0; t < 7; ++t)
#pragma unroll
        for (int r = 0; r < 4; ++r) {
            int row = t * 16 + quad * 4 + r;
            if (row < NNODES)
                atomicAdd(&Yb[row * YW + c0 + n16], acc[t][r]);
        }
}

// ---------------- fallback f32 GEMM (used only if ws is too small) -------------
__global__ __launch_bounds__(256, 2) void k_gemm_f32(const float* __restrict__ x,
                                                     const float* __restrict__ wa,
                                                     const float* __restrict__ wc,
                                                     float* __restrict__ Y) {
    const int hk   = blockIdx.x;
    const int kc   = blockIdx.y;
    const int wave = threadIdx.x >> 6;
    const int lane = threadIdx.x & 63;
    const int n16  = lane & 15;
    const int quad = lane >> 4;
    const float* W = (hk < 3 ? wa : wc) + (size_t)(hk % 3) * ((size_t)KDIM * OUTC);
    const int c0   = wave * 16;
    const int cidx = min(c0 + n16, OUTC - 1);
    const int kb0  = kc * CHUNK + quad * 8;
    const float* ap[7];
#pragma unroll
    for (int t = 0; t < 7; ++t)
        ap[t] = x + (size_t)min(n16 + 16 * t, NNODES - 1) * KDIM + kb0;
    const float* bp = W + (size_t)kb0 * OUTC + cidx;
    f32x4 acc[7] = {};
#pragma unroll 2
    for (int s = 0; s < STEPS; ++s) {
        bf16x8 bfr;
        const float* qq = bp + (size_t)s * 32 * OUTC;
#pragma unroll
        for (int j = 0; j < 8; ++j) bfr[j] = (short)f2bf(qq[j * OUTC]);
#pragma unroll
        for (int t = 0; t < 7; ++t) {
            const float* p = ap[t] + s * 32;
            float4 lo = *(const float4*)p;
            float4 hi = *(const float4*)(p + 4);
            bf16x8 afr;
            afr[0] = (short)f2bf(lo.x); afr[1] = (short)f2bf(lo.y);
            afr[2] = (short)f2bf(lo.z); afr[3] = (short)f2bf(lo.w);
            afr[4] = (short)f2bf(hi.x); afr[5] = (short)f2bf(hi.y);
            afr[6] = (short)f2bf(hi.z); afr[7] = (short)f2bf(hi.w);
            acc[t] = __builtin_amdgcn_mfma_f32_16x16x32_bf16(afr, bfr, acc[t], 0, 0, 0);
        }
    }
    float* Yb = Y + hk * YSLAB;
#pragma unroll
    for (int t = 0; t < 7; ++t)
#pragma unroll
        for (int r = 0; r < 4; ++r) {
            int row = t * 16 + quad * 4 + r;
            if (row < NNODES)
                atomicAdd(&Yb[row * YW + c0 + n16], acc[t][r]);
        }
}

// ------- kernel 3: build S in LDS + emb = tanh(cheb) + vnr  (fused) ------------
__global__ __launch_bounds__(128) void k_emb(const int* __restrict__ ei,
                                             const float* __restrict__ Y,
                                             const float* __restrict__ vnr,
                                             const float* __restrict__ avw,
                                             const float* __restrict__ avb,
                                             const float* __restrict__ cvw,
                                             const float* __restrict__ cvb,
                                             const float* __restrict__ acb,
                                             const float* __restrict__ ccb,
                                             const float* __restrict__ afcb,
                                             const float* __restrict__ cfcb,
                                             float* __restrict__ E,
                                             float* __restrict__ out) {
    __shared__ float Sp[NNODES * 101];
    __shared__ float y0[NNODES], y1[NNODES], y2[NNODES], t2[NNODES];
    __shared__ int   deg[NNODES];
    __shared__ float dinv[NNODES];
    const int b = blockIdx.x, head = b / OUTC, c = b % OUTC;
    const int t = threadIdx.x;
    const int* src = ei;
    const int* dst = ei + 1600;

    for (int i = t; i < NNODES * 101; i += 128) Sp[i] = 0.f;
    if (t < NNODES) deg[t] = 0;
    __syncthreads();
    for (int e = t; e < 1600; e += 128) atomicAdd(&deg[src[e]], 1);
    __syncthreads();
    if (t < NNODES) { int d = deg[t]; dinv[t] = (d > 0) ? rsqrtf((float)d) : 0.f; }
    __syncthreads();
    for (int e = t; e < 1600; e += 128) {
        int s = src[e], d = dst[e];
        atomicAdd(&Sp[d * 101 + s], -dinv[s] * dinv[d]);
    }
    const float* Yh = Y + (size_t)head * 3 * YSLAB;
    if (t < NNODES) {
        y0[t] = Yh[t * YW + c];
        y1[t] = Yh[YSLAB + t * YW + c];
        y2[t] = Yh[2 * YSLAB + t * YW + c];
    }
    if (b == 0 && t < 101) out[t] = (t < 100) ? afcb[t] : cfcb[0];
    __syncthreads();

    float z1 = 0.f, s2 = 0.f;
    if (t < NNODES) {
        const float* sr = Sp + t * 101;
        for (int m = 0; m < NNODES; ++m) { z1 += sr[m] * y1[m]; s2 += sr[m] * y2[m]; }
        t2[t] = s2;
    }
    __syncthreads();
    if (t < NNODES) {
        const float* sr = Sp + t * 101;
        float t3 = 0.f;
        for (int m = 0; m < NNODES; ++m) t3 += sr[m] * t2[m];
        const float* cb = head ? ccb : acb;
        const float* vw = head ? cvw : avw;
        const float* vb = head ? cvb : avb;
        float u  = y0[t] + z1 + 2.f * t3 - y2[t] + cb[c];
        float vs = vnr[0] * vw[c]        + vb[c]
                 + vnr[1] * vw[OUTC + c] + vb[OUTC + c]
                 + vnr[2] * vw[2*OUTC+c] + vb[2*OUTC+c];
        E[head * (NNODES * OUTC) + t * OUTC + c] = tanhf(u) + vs;
    }
}

// ---------------- kernel 4: heads — grid 240, 25 flat rows per block -----------
__global__ __launch_bounds__(128) void k_heads(const float* __restrict__ E,
                                               const float* __restrict__ afw,
                                               const float* __restrict__ cfw,
                                               float* __restrict__ out) {
    __shared__ float ea[25], ec[25];
    const int b = blockIdx.x, t = threadIdx.x;
    const int f0 = b * 25;
    if (t < 25) {
        ea[t] = E[f0 + t];
        ec[t] = E[NNODES * OUTC + f0 + t];
    }
    __syncthreads();
    if (t < 100) {
        float s = 0.f;
#pragma unroll
        for (int i = 0; i < 25; ++i) s += ea[i] * afw[(size_t)(f0 + i) * 100 + t];
        atomicAdd(&out[t], s);
    } else if (t == 100) {
        float s = 0.f;
#pragma unroll
        for (int i = 0; i < 25; ++i) s += ec[i] * cfw[f0 + i];
        atomicAdd(&out[100], s);
    }
}

// ---------------- launch ----------------
extern "C" void kernel_launch(void* const* d_in, const int* in_sizes, int n_in,
                              void* d_out, int out_size, void* d_ws, size_t ws_size,
                              hipStream_t stream) {
    const float* x    = (const float*)d_in[0];
    const int*   ei   = (const int*)  d_in[1];
    const float* vnr  = (const float*)d_in[2];
    const float* wa   = (const float*)d_in[3];
    const float* acb  = (const float*)d_in[4];
    const float* wc   = (const float*)d_in[5];
    const float* ccb  = (const float*)d_in[6];
    const float* avw  = (const float*)d_in[7];
    const float* avb  = (const float*)d_in[8];
    const float* cvw  = (const float*)d_in[9];
    const float* cvb  = (const float*)d_in[10];
    const float* afw  = (const float*)d_in[11];
    const float* afcb = (const float*)d_in[12];
    const float* cfw  = (const float*)d_in[13];
    const float* cfcb = (const float*)d_in[14];

    float* ws = (float*)d_ws;
    float* Y  = ws + WS_Y;
    float* E  = ws + WS_E;
    float* out = (float*)d_out;

    if (ws_size >= WS_NEED_BYTES) {
        unsigned short* xb = (unsigned short*)((char*)d_ws + XB_OFF_BYTES);
        k_cvt_x<<<800, 256, 0, stream>>>(x, (ushort8*)xb, Y);   // also zeroes Y
        k_gemm7<<<384, 256, 0, stream>>>(xb, wa, wc, Y);
    } else {
        hipMemsetAsync((char*)d_ws + WS_Y * 4, 0, (WS_E - WS_Y) * 4, stream);
        k_gemm_f32<<<dim3(6, NKC), 256, 0, stream>>>(x, wa, wc, Y);
    }

    k_emb<<<120, 128, 0, stream>>>(ei, Y, vnr, avw, avb, cvw, cvb,
                                   acb, ccb, afcb, cfcb, E, out);
    k_heads<<<240, 128, 0, stream>>>(E, afw, cfw, out);
}